// Round 3
// baseline (1317.487 us; speedup 1.0000x reference)
//
#include <hip/hip_runtime.h>
#include <cstdint>
#include <cstddef>

#define S_LEN 2048
#define EMB   1024
#define NH    16
#define HD    64
#define E3    3072   // 3*EMB

// ---------------------------------------------------------------------------
// GEMM: C[M,N] = X[M,K] @ W[N,K]^T + bias[N]
// Both X and W are row-major with K contiguous (NT gemm, dot of rows).
// 128x128 tile, BK=16, 256 threads, 8x8 micro-tile per thread.
// ---------------------------------------------------------------------------
__global__ __launch_bounds__(256, 2) void gemm_nt_bias(
    const float* __restrict__ X, const float* __restrict__ W,
    const float* __restrict__ bias, float* __restrict__ C,
    int M, int N, int K)
{
    const int BK = 16;
    __shared__ float As[BK][128];   // [k][m]
    __shared__ float Bs[BK][128];   // [k][n]

    const int t  = threadIdx.x;
    const int tx = t & 15;          // n-group
    const int ty = t >> 4;          // m-group
    const int row0 = blockIdx.y * 128;
    const int col0 = blockIdx.x * 128;

    const float* Xp = X + (size_t)row0 * K;
    const float* Wp = W + (size_t)col0 * K;

    float acc[8][8];
#pragma unroll
    for (int i = 0; i < 8; ++i)
#pragma unroll
        for (int j = 0; j < 8; ++j) acc[i][j] = 0.0f;

    for (int k0 = 0; k0 < K; k0 += BK) {
        __syncthreads();
#pragma unroll
        for (int rep = 0; rep < 2; ++rep) {
            int idx = rep * 256 + t;
            int r = idx >> 2;             // 0..127 tile row
            int c = (idx & 3) << 2;       // 0,4,8,12
            float4 a = *(const float4*)(Xp + (size_t)r * K + k0 + c);
            float4 b = *(const float4*)(Wp + (size_t)r * K + k0 + c);
            As[c + 0][r] = a.x; As[c + 1][r] = a.y; As[c + 2][r] = a.z; As[c + 3][r] = a.w;
            Bs[c + 0][r] = b.x; Bs[c + 1][r] = b.y; Bs[c + 2][r] = b.z; Bs[c + 3][r] = b.w;
        }
        __syncthreads();
#pragma unroll
        for (int kk = 0; kk < BK; ++kk) {
            float a[8], b[8];
            *(float4*)&a[0] = *(const float4*)&As[kk][(ty << 2)];
            *(float4*)&a[4] = *(const float4*)&As[kk][64 + (ty << 2)];
            *(float4*)&b[0] = *(const float4*)&Bs[kk][(tx << 2)];
            *(float4*)&b[4] = *(const float4*)&Bs[kk][64 + (tx << 2)];
#pragma unroll
            for (int i = 0; i < 8; ++i)
#pragma unroll
                for (int j = 0; j < 8; ++j)
                    acc[i][j] = fmaf(a[i], b[j], acc[i][j]);
        }
    }

    // epilogue: bias add + store
#pragma unroll
    for (int ih = 0; ih < 2; ++ih)
#pragma unroll
        for (int i = 0; i < 4; ++i) {
            int r = row0 + ih * 64 + (ty << 2) + i;
#pragma unroll
            for (int jh = 0; jh < 2; ++jh) {
                int c = col0 + jh * 64 + (tx << 2);
                float4 bb = *(const float4*)(bias + c);
                float4 o;
                o.x = acc[ih * 4 + i][jh * 4 + 0] + bb.x;
                o.y = acc[ih * 4 + i][jh * 4 + 1] + bb.y;
                o.z = acc[ih * 4 + i][jh * 4 + 2] + bb.z;
                o.w = acc[ih * 4 + i][jh * 4 + 3] + bb.w;
                *(float4*)(C + (size_t)r * N + c) = o;
            }
        }
}

// ---------------------------------------------------------------------------
// Flash-style attention, fp32.
// Grid: (S/64 q-blocks, B*H). Block: 256 threads (16x16).
// Thread (ty,tx): scores/acc for q-rows {4ty+i}, score cols {tx+16j},
// output cols {4tx+j}. LDS rows stride 68 floats (=4 mod 32 -> <=2-way banks,
// 16B aligned). P overlays K buffer (fits 64KB static LDS; 3 blocks/CU).
// ---------------------------------------------------------------------------
__global__ __launch_bounds__(256, 2) void attn_fwd(
    const float* __restrict__ qkv, const float* __restrict__ mask,
    float* __restrict__ yout)
{
    __shared__ float Qs[64][68];
    __shared__ float KPs[64][68];   // K tile during scores, P tile during PV
    __shared__ float Vs[64][68];

    const int t  = threadIdx.x;
    const int tx = t & 15;
    const int ty = t >> 4;
    const int qb = blockIdx.x;           // 0..31
    const int bh = blockIdx.y;           // 0..31
    const int b  = bh >> 4, h = bh & 15;

    const float* Qg = qkv + (size_t)b * S_LEN * E3 + h * HD;
    const float* Kg = Qg + EMB;
    const float* Vg = Qg + 2 * EMB;
    const float* Mg = mask + (size_t)b * S_LEN * S_LEN + (size_t)qb * 64 * S_LEN;

    // load Q tile, pre-scaled by 1/sqrt(D) = 0.125
#pragma unroll
    for (int rep = 0; rep < 4; ++rep) {
        int idx = rep * 256 + t;
        int r = idx >> 4, c = (idx & 15) << 2;
        float4 q = *(const float4*)(Qg + (size_t)(qb * 64 + r) * E3 + c);
        q.x *= 0.125f; q.y *= 0.125f; q.z *= 0.125f; q.w *= 0.125f;
        *(float4*)&Qs[r][c] = q;
    }

    float m_run[4], l_run[4], acc[4][4];
#pragma unroll
    for (int i = 0; i < 4; ++i) {
        m_run[i] = -3.0e38f; l_run[i] = 0.0f;
#pragma unroll
        for (int j = 0; j < 4; ++j) acc[i][j] = 0.0f;
    }

    for (int k0 = 0; k0 < S_LEN; k0 += 64) {
        __syncthreads();  // prev tile's PV reads done (and Q store on iter 0)
#pragma unroll
        for (int rep = 0; rep < 4; ++rep) {
            int idx = rep * 256 + t;
            int r = idx >> 4, c = (idx & 15) << 2;
            *(float4*)&KPs[r][c] = *(const float4*)(Kg + (size_t)(k0 + r) * E3 + c);
            *(float4*)&Vs[r][c]  = *(const float4*)(Vg + (size_t)(k0 + r) * E3 + c);
        }
        __syncthreads();

        // scores: s[i][j] = q_row(4ty+i) . k_row(tx+16j)
        float s[4][4];
#pragma unroll
        for (int i = 0; i < 4; ++i)
#pragma unroll
            for (int j = 0; j < 4; ++j) s[i][j] = 0.0f;

#pragma unroll
        for (int d0 = 0; d0 < 64; d0 += 4) {
            float4 q4[4], k4[4];
#pragma unroll
            for (int i = 0; i < 4; ++i) q4[i] = *(const float4*)&Qs[(ty << 2) + i][d0];
#pragma unroll
            for (int j = 0; j < 4; ++j) k4[j] = *(const float4*)&KPs[tx + (j << 4)][d0];
#pragma unroll
            for (int i = 0; i < 4; ++i)
#pragma unroll
                for (int j = 0; j < 4; ++j)
                    s[i][j] += q4[i].x * k4[j].x + q4[i].y * k4[j].y
                             + q4[i].z * k4[j].z + q4[i].w * k4[j].w;
        }

        // additive mask (reference: p + mask * -10000)
#pragma unroll
        for (int i = 0; i < 4; ++i)
#pragma unroll
            for (int j = 0; j < 4; ++j)
                s[i][j] += Mg[(size_t)((ty << 2) + i) * S_LEN + k0 + tx + (j << 4)] * (-10000.0f);

        __syncthreads();  // all score reads of KPs done before P overwrite

        // online softmax; write P into KPs
#pragma unroll
        for (int i = 0; i < 4; ++i) {
            float mt = fmaxf(fmaxf(s[i][0], s[i][1]), fmaxf(s[i][2], s[i][3]));
#pragma unroll
            for (int off = 1; off < 16; off <<= 1) mt = fmaxf(mt, __shfl_xor(mt, off, 16));
            float mn   = fmaxf(m_run[i], mt);
            float corr = __expf(m_run[i] - mn);
            float ps = 0.0f;
#pragma unroll
            for (int j = 0; j < 4; ++j) {
                float p = __expf(s[i][j] - mn);
                KPs[(ty << 2) + i][tx + (j << 4)] = p;
                ps += p;
            }
#pragma unroll
            for (int off = 1; off < 16; off <<= 1) ps += __shfl_xor(ps, off, 16);
            l_run[i] = l_run[i] * corr + ps;
            m_run[i] = mn;
#pragma unroll
            for (int j = 0; j < 4; ++j) acc[i][j] *= corr;
        }
        __syncthreads();  // P visible to all

        // PV: acc[i][j] += P[4ty+i][kk] * V[kk][4tx+j]
#pragma unroll
        for (int kk = 0; kk < 64; kk += 4) {
            float4 p4[4], v4[4];
#pragma unroll
            for (int i = 0; i < 4; ++i) p4[i] = *(const float4*)&KPs[(ty << 2) + i][kk];
#pragma unroll
            for (int l = 0; l < 4; ++l) v4[l] = *(const float4*)&Vs[kk + l][(tx << 2)];
#pragma unroll
            for (int i = 0; i < 4; ++i) {
                const float* pf = (const float*)&p4[i];
#pragma unroll
                for (int l = 0; l < 4; ++l) {
                    const float* vf = (const float*)&v4[l];
#pragma unroll
                    for (int j = 0; j < 4; ++j)
                        acc[i][j] = fmaf(pf[l], vf[j], acc[i][j]);
                }
            }
        }
    }

    // epilogue: normalize by l, store to [B,S,E] layout (head h at cols h*64..)
#pragma unroll
    for (int i = 0; i < 4; ++i) {
        float inv = 1.0f / l_run[i];
        float4 o;
        o.x = acc[i][0] * inv; o.y = acc[i][1] * inv;
        o.z = acc[i][2] * inv; o.w = acc[i][3] * inv;
        *(float4*)(yout + (size_t)b * S_LEN * EMB
                        + (size_t)(qb * 64 + (ty << 2) + i) * EMB
                        + h * HD + (tx << 2)) = o;
    }
}

// ---------------------------------------------------------------------------
extern "C" void kernel_launch(void* const* d_in, const int* in_sizes, int n_in,
                              void* d_out, int out_size, void* d_ws, size_t ws_size,
                              hipStream_t stream)
{
    const float* x     = (const float*)d_in[0];
    const float* mask  = (const float*)d_in[1];
    const float* w_in  = (const float*)d_in[2];
    const float* b_in  = (const float*)d_in[3];
    const float* w_out = (const float*)d_in[4];
    const float* b_out = (const float*)d_in[5];
    float* out = (float*)d_out;

    float* qkv   = (float*)d_ws;                       // [4096][3072] = 50.3 MB
    float* yattn = qkv + (size_t)4096 * E3;            // [4096][1024] = 16.8 MB

    // 1) fused QKV projection: qkv = x @ in_proj_weight^T + in_proj_bias
    gemm_nt_bias<<<dim3(E3 / 128, 4096 / 128), 256, 0, stream>>>(
        x, w_in, b_in, qkv, 4096, E3, EMB);

    // 2) flash attention -> [B,S,E]
    attn_fwd<<<dim3(S_LEN / 64, 2 * NH), 256, 0, stream>>>(qkv, mask, yattn);

    // 3) output projection: out = yattn @ out_proj_weight^T + out_proj_bias
    gemm_nt_bias<<<dim3(EMB / 128, 4096 / 128), 256, 0, stream>>>(
        yattn, w_out, b_out, out, 4096, EMB, EMB);
}

// Round 4
// 986.692 us; speedup vs baseline: 1.3353x; 1.3353x over previous
//
#include <hip/hip_runtime.h>
#include <cstdint>
#include <cstddef>

#define S_LEN 2048
#define EMB   1024
#define NH    16
#define HD    64
#define E3    3072   // 3*EMB

typedef __attribute__((ext_vector_type(8))) short b16x8;   // 8 bf16 = 4 VGPR (MFMA A/B frag)
typedef __attribute__((ext_vector_type(4))) float f32x4;   // MFMA C/D frag

// ---- bf16 split helpers (RNE via bit ops; data is finite) -------------------
__device__ __forceinline__ ushort bf16_rne(float f) {
    uint32_t u = __float_as_uint(f);
    uint32_t r = (u + 0x7FFFu + ((u >> 16) & 1u)) >> 16;
    return (ushort)r;
}
__device__ __forceinline__ void split2(float f, ushort* h, ushort* l) {
    ushort hh = bf16_rne(f);
    *h = hh;
    float rem = f - __uint_as_float(((uint32_t)hh) << 16);
    *l = bf16_rne(rem);
}

// ---- fp32 -> (bf16 hi, bf16 lo) elementwise ---------------------------------
__global__ __launch_bounds__(256) void split_f32_kernel(
    const float4* __restrict__ src, ushort4* __restrict__ h,
    ushort4* __restrict__ l, int n4)
{
    int i = blockIdx.x * 256 + threadIdx.x;
    if (i >= n4) return;
    float4 v = src[i];
    ushort4 hv, lv;
    split2(v.x, &hv.x, &lv.x);
    split2(v.y, &hv.y, &lv.y);
    split2(v.z, &hv.z, &lv.z);
    split2(v.w, &hv.w, &lv.w);
    h[i] = hv; l[i] = lv;
}

// ---- async 16B global->LDS --------------------------------------------------
__device__ __forceinline__ void gload16(const void* g, void* lds) {
    __builtin_amdgcn_global_load_lds(
        (const __attribute__((address_space(1))) uint32_t*)g,
        (__attribute__((address_space(3))) uint32_t*)lds, 16, 0, 0);
}

// ---------------------------------------------------------------------------
// Split-bf16 MFMA GEMM: C[M,N] = A[M,K] @ B[N,K]^T + bias[N]  (fp32-accurate)
// A,B given as bf16 hi/lo pairs (row-major, K contiguous).
// 128x128 tile, BK=64, 256 thr = 4 waves (2x2), wave = 64x64 = 4x4 frags of
// 16x16x32. 3 MFMA per frag pair: Ah*Bh + Ah*Bl + Al*Bh (lo*lo dropped).
// LDS: 4 tiles [128 rows][64 bf16] = 64KB, linear dest for global_load_lds;
// XOR slot-swizzle (slot^= row&7) applied on the per-lane GLOBAL address and
// again on the LDS read -> frag ds_read_b128 is 2-way (free) not 16-way.
// ---------------------------------------------------------------------------
__global__ __launch_bounds__(256, 2) void gemm_split_bf16(
    const ushort* __restrict__ Ah, const ushort* __restrict__ Al,
    const ushort* __restrict__ Bh, const ushort* __restrict__ Bl,
    const float* __restrict__ bias, float* __restrict__ C,
    int M, int N, int K)
{
    __shared__ __align__(16) ushort ldsT[4][128 * 64];   // Ah, Al, Bh, Bl

    const int t    = threadIdx.x;
    const int lane = t & 63;
    const int wave = t >> 6;
    const int wm   = wave >> 1, wn = wave & 1;
    const int bm0  = blockIdx.y * 128, bn0 = blockIdx.x * 128;

    f32x4 acc[4][4];
#pragma unroll
    for (int i = 0; i < 4; ++i)
#pragma unroll
        for (int j = 0; j < 4; ++j) acc[i][j] = (f32x4){0.f, 0.f, 0.f, 0.f};

    for (int k0 = 0; k0 < K; k0 += 64) {
        __syncthreads();   // previous iteration's LDS reads complete
#pragma unroll
        for (int rep = 0; rep < 16; ++rep) {
            const int tile = rep >> 2;                  // 0:Ah 1:Al 2:Bh 3:Bl
            const int sig  = (rep & 3) * 256 + t;       // 0..1023 linear slot
            const int row  = sig >> 3;                  // 0..127
            const int slot = sig & 7;
            const int slog = slot ^ (row & 7);          // pre-swizzled source slot
            const ushort* src = (tile == 0) ? Ah : (tile == 1) ? Al
                              : (tile == 2) ? Bh : Bl;
            const int rb = (tile < 2) ? bm0 : bn0;
            gload16(src + (size_t)(rb + row) * K + k0 + slog * 8,
                    &ldsT[tile][sig * 8]);
        }
        __syncthreads();   // staging complete (vmcnt(0) before barrier)

#pragma unroll
        for (int s = 0; s < 2; ++s) {                   // two K=32 slices
            b16x8 af[4][2], bf[4][2];
#pragma unroll
            for (int i = 0; i < 4; ++i) {
                const int rA = wm * 64 + i * 16 + (lane & 15);
                const int sA = (s * 4 + (lane >> 4)) ^ (rA & 7);
                af[i][0] = *(const b16x8*)&ldsT[0][rA * 64 + sA * 8];
                af[i][1] = *(const b16x8*)&ldsT[1][rA * 64 + sA * 8];
                const int rB = wn * 64 + i * 16 + (lane & 15);
                const int sB = (s * 4 + (lane >> 4)) ^ (rB & 7);
                bf[i][0] = *(const b16x8*)&ldsT[2][rB * 64 + sB * 8];
                bf[i][1] = *(const b16x8*)&ldsT[3][rB * 64 + sB * 8];
            }
#pragma unroll
            for (int i = 0; i < 4; ++i)
#pragma unroll
                for (int j = 0; j < 4; ++j) {
                    acc[i][j] = __builtin_amdgcn_mfma_f32_16x16x32_bf16(
                        af[i][0], bf[j][0], acc[i][j], 0, 0, 0);
                    acc[i][j] = __builtin_amdgcn_mfma_f32_16x16x32_bf16(
                        af[i][0], bf[j][1], acc[i][j], 0, 0, 0);
                    acc[i][j] = __builtin_amdgcn_mfma_f32_16x16x32_bf16(
                        af[i][1], bf[j][0], acc[i][j], 0, 0, 0);
                }
        }
    }

    // epilogue: C row = (lane>>4)*4+reg, col = lane&15 (verified m89/m91 layout)
#pragma unroll
    for (int i = 0; i < 4; ++i) {
        const int row = bm0 + wm * 64 + i * 16 + (lane >> 4) * 4;
#pragma unroll
        for (int j = 0; j < 4; ++j) {
            const int col = bn0 + wn * 64 + j * 16 + (lane & 15);
            const float bv = bias[col];
#pragma unroll
            for (int r = 0; r < 4; ++r)
                C[(size_t)(row + r) * N + col] = acc[i][j][r] + bv;
        }
    }
}

// ---------------------------------------------------------------------------
// Flash-style attention, fp32 (unchanged math). Now 3 blocks/CU and epilogue
// emits Y as bf16 hi/lo pairs for the split-bf16 out-projection.
// ---------------------------------------------------------------------------
__global__ __launch_bounds__(256, 3) void attn_fwd(
    const float* __restrict__ qkv, const float* __restrict__ mask,
    ushort* __restrict__ Yh, ushort* __restrict__ Yl)
{
    __shared__ float Qs[64][68];
    __shared__ float KPs[64][68];   // K tile during scores, P tile during PV
    __shared__ float Vs[64][68];

    const int t  = threadIdx.x;
    const int tx = t & 15;
    const int ty = t >> 4;
    const int qb = blockIdx.x;
    const int bh = blockIdx.y;
    const int b  = bh >> 4, h = bh & 15;

    const float* Qg = qkv + (size_t)b * S_LEN * E3 + h * HD;
    const float* Kg = Qg + EMB;
    const float* Vg = Qg + 2 * EMB;
    const float* Mg = mask + (size_t)b * S_LEN * S_LEN + (size_t)qb * 64 * S_LEN;

#pragma unroll
    for (int rep = 0; rep < 4; ++rep) {
        int idx = rep * 256 + t;
        int r = idx >> 4, c = (idx & 15) << 2;
        float4 q = *(const float4*)(Qg + (size_t)(qb * 64 + r) * E3 + c);
        q.x *= 0.125f; q.y *= 0.125f; q.z *= 0.125f; q.w *= 0.125f;
        *(float4*)&Qs[r][c] = q;
    }

    float m_run[4], l_run[4], acc[4][4];
#pragma unroll
    for (int i = 0; i < 4; ++i) {
        m_run[i] = -3.0e38f; l_run[i] = 0.0f;
#pragma unroll
        for (int j = 0; j < 4; ++j) acc[i][j] = 0.0f;
    }

    for (int k0 = 0; k0 < S_LEN; k0 += 64) {
        __syncthreads();
#pragma unroll
        for (int rep = 0; rep < 4; ++rep) {
            int idx = rep * 256 + t;
            int r = idx >> 4, c = (idx & 15) << 2;
            *(float4*)&KPs[r][c] = *(const float4*)(Kg + (size_t)(k0 + r) * E3 + c);
            *(float4*)&Vs[r][c]  = *(const float4*)(Vg + (size_t)(k0 + r) * E3 + c);
        }
        __syncthreads();

        float s[4][4];
#pragma unroll
        for (int i = 0; i < 4; ++i)
#pragma unroll
            for (int j = 0; j < 4; ++j) s[i][j] = 0.0f;

#pragma unroll
        for (int d0 = 0; d0 < 64; d0 += 4) {
            float4 q4[4], k4[4];
#pragma unroll
            for (int i = 0; i < 4; ++i) q4[i] = *(const float4*)&Qs[(ty << 2) + i][d0];
#pragma unroll
            for (int j = 0; j < 4; ++j) k4[j] = *(const float4*)&KPs[tx + (j << 4)][d0];
#pragma unroll
            for (int i = 0; i < 4; ++i)
#pragma unroll
                for (int j = 0; j < 4; ++j)
                    s[i][j] += q4[i].x * k4[j].x + q4[i].y * k4[j].y
                             + q4[i].z * k4[j].z + q4[i].w * k4[j].w;
        }

#pragma unroll
        for (int i = 0; i < 4; ++i)
#pragma unroll
            for (int j = 0; j < 4; ++j)
                s[i][j] += Mg[(size_t)((ty << 2) + i) * S_LEN + k0 + tx + (j << 4)] * (-10000.0f);

        __syncthreads();

#pragma unroll
        for (int i = 0; i < 4; ++i) {
            float mt = fmaxf(fmaxf(s[i][0], s[i][1]), fmaxf(s[i][2], s[i][3]));
#pragma unroll
            for (int off = 1; off < 16; off <<= 1) mt = fmaxf(mt, __shfl_xor(mt, off, 16));
            float mn   = fmaxf(m_run[i], mt);
            float corr = __expf(m_run[i] - mn);
            float ps = 0.0f;
#pragma unroll
            for (int j = 0; j < 4; ++j) {
                float p = __expf(s[i][j] - mn);
                KPs[(ty << 2) + i][tx + (j << 4)] = p;
                ps += p;
            }
#pragma unroll
            for (int off = 1; off < 16; off <<= 1) ps += __shfl_xor(ps, off, 16);
            l_run[i] = l_run[i] * corr + ps;
            m_run[i] = mn;
#pragma unroll
            for (int j = 0; j < 4; ++j) acc[i][j] *= corr;
        }
        __syncthreads();

#pragma unroll
        for (int kk = 0; kk < 64; kk += 4) {
            float4 p4[4], v4[4];
#pragma unroll
            for (int i = 0; i < 4; ++i) p4[i] = *(const float4*)&KPs[(ty << 2) + i][kk];
#pragma unroll
            for (int l = 0; l < 4; ++l) v4[l] = *(const float4*)&Vs[kk + l][(tx << 2)];
#pragma unroll
            for (int i = 0; i < 4; ++i) {
                const float* pf = (const float*)&p4[i];
#pragma unroll
                for (int l = 0; l < 4; ++l) {
                    const float* vf = (const float*)&v4[l];
#pragma unroll
                    for (int j = 0; j < 4; ++j)
                        acc[i][j] = fmaf(pf[l], vf[j], acc[i][j]);
                }
            }
        }
    }

    // epilogue: normalize, split to bf16 hi/lo for the out-projection
#pragma unroll
    for (int i = 0; i < 4; ++i) {
        float inv = 1.0f / l_run[i];
        ushort4 hv, lv;
        float o0 = acc[i][0] * inv, o1 = acc[i][1] * inv;
        float o2 = acc[i][2] * inv, o3 = acc[i][3] * inv;
        split2(o0, &hv.x, &lv.x);
        split2(o1, &hv.y, &lv.y);
        split2(o2, &hv.z, &lv.z);
        split2(o3, &hv.w, &lv.w);
        size_t off = ((size_t)b * S_LEN + qb * 64 + (ty << 2) + i) * EMB
                   + h * HD + (tx << 2);
        *(ushort4*)(Yh + off) = hv;
        *(ushort4*)(Yl + off) = lv;
    }
}

// ---------------------------------------------------------------------------
extern "C" void kernel_launch(void* const* d_in, const int* in_sizes, int n_in,
                              void* d_out, int out_size, void* d_ws, size_t ws_size,
                              hipStream_t stream)
{
    const float* x     = (const float*)d_in[0];
    const float* mask  = (const float*)d_in[1];
    const float* w_in  = (const float*)d_in[2];
    const float* b_in  = (const float*)d_in[3];
    const float* w_out = (const float*)d_in[4];
    const float* b_out = (const float*)d_in[5];
    float* out = (float*)d_out;

    // workspace layout (83.9 MB total):
    char* ws = (char*)d_ws;
    float*  qkv = (float*)ws;                          // 4096x3072 f32 = 50.33 MB
    ushort* Xh  = (ushort*)(ws + 50331648);            // 4096x1024 bf16 = 8.39 MB
    ushort* Xl  = (ushort*)(ws + 58720256);
    ushort* Wih = (ushort*)(ws + 67108864);            // 3072x1024 bf16 = 6.29 MB
    ushort* Wil = (ushort*)(ws + 73400320);
    ushort* Woh = (ushort*)(ws + 79691776);            // 1024x1024 bf16 = 2.10 MB
    ushort* Wol = (ushort*)(ws + 81788928);
    // Y (attn output) overlays X -- X is dead after the QKV projection.
    ushort* Yh = Xh;
    ushort* Yl = Xl;

    // 0) split fp32 -> bf16 hi/lo (X, W_in, W_out)
    split_f32_kernel<<<4096, 256, 0, stream>>>((const float4*)x,
        (ushort4*)Xh, (ushort4*)Xl, 1048576);
    split_f32_kernel<<<3072, 256, 0, stream>>>((const float4*)w_in,
        (ushort4*)Wih, (ushort4*)Wil, 786432);
    split_f32_kernel<<<1024, 256, 0, stream>>>((const float4*)w_out,
        (ushort4*)Woh, (ushort4*)Wol, 262144);

    // 1) QKV projection (split-bf16 MFMA): qkv = x @ W_in^T + b_in
    gemm_split_bf16<<<dim3(E3 / 128, 4096 / 128), 256, 0, stream>>>(
        Xh, Xl, Wih, Wil, b_in, qkv, 4096, E3, EMB);

    // 2) flash attention (fp32) -> Y as bf16 hi/lo
    attn_fwd<<<dim3(S_LEN / 64, 2 * NH), 256, 0, stream>>>(qkv, mask, Yh, Yl);

    // 3) out projection (split-bf16 MFMA): out = Y @ W_out^T + b_out
    gemm_split_bf16<<<dim3(EMB / 128, 4096 / 128), 256, 0, stream>>>(
        Yh, Yl, Woh, Wol, b_out, out, 4096, EMB, EMB);
}

// Round 7
// 391.957 us; speedup vs baseline: 3.3613x; 2.5173x over previous
//
#include <hip/hip_runtime.h>
#include <cstdint>
#include <cstddef>

#define S_LEN 2048
#define EMB   1024
#define NH    16
#define HD    64
#define E3    3072   // 3*EMB

typedef __attribute__((ext_vector_type(8))) short b16x8;   // 8 bf16 = 4 VGPR (MFMA A/B frag)
typedef __attribute__((ext_vector_type(4))) float f32x4;   // MFMA C/D frag

// ---- bf16 split helpers (RNE via bit ops; data is finite) -------------------
__device__ __forceinline__ ushort bf16_rne(float f) {
    uint32_t u = __float_as_uint(f);
    uint32_t r = (u + 0x7FFFu + ((u >> 16) & 1u)) >> 16;
    return (ushort)r;
}
__device__ __forceinline__ void split2(float f, ushort* h, ushort* l) {
    ushort hh = bf16_rne(f);
    *h = hh;
    float rem = f - __uint_as_float(((uint32_t)hh) << 16);
    *l = bf16_rne(rem);
}

// ---- fp32 -> (bf16 hi, bf16 lo) elementwise ---------------------------------
__global__ __launch_bounds__(256) void split_f32_kernel(
    const float4* __restrict__ src, ushort4* __restrict__ h,
    ushort4* __restrict__ l, int n4)
{
    int i = blockIdx.x * 256 + threadIdx.x;
    if (i >= n4) return;
    float4 v = src[i];
    ushort4 hv, lv;
    split2(v.x, &hv.x, &lv.x);
    split2(v.y, &hv.y, &lv.y);
    split2(v.z, &hv.z, &lv.z);
    split2(v.w, &hv.w, &lv.w);
    h[i] = hv; l[i] = lv;
}

// ---- async 16B global->LDS --------------------------------------------------
__device__ __forceinline__ void gload16(const void* g, void* lds) {
    __builtin_amdgcn_global_load_lds(
        (const __attribute__((address_space(1))) uint32_t*)g,
        (__attribute__((address_space(3))) uint32_t*)lds, 16, 0, 0);
}

// ---------------------------------------------------------------------------
// QKV projection GEMM (split-bf16, 3-MFMA): qkv = X @ Win^T + b_in.
// M=4096, N=3072, K=1024. Epilogue: Q cols (<1024) scaled 1/8, Q,K written as
// split bf16 row-major [4096][2048]; V cols written TRANSPOSED per head:
// Vt[b*16+h][d][s] (split bf16) so attention's PV B-operand is kv-contiguous.
// ---------------------------------------------------------------------------
__global__ __launch_bounds__(256, 2) void gemm_qkv(
    const ushort* __restrict__ Ah, const ushort* __restrict__ Al,
    const ushort* __restrict__ Bh, const ushort* __restrict__ Bl,
    const float* __restrict__ bias,
    ushort* __restrict__ qkvh, ushort* __restrict__ qkvl,
    ushort* __restrict__ Vth, ushort* __restrict__ Vtl)
{
    const int K = 1024;
    __shared__ __align__(16) ushort ldsT[4][128 * 64];   // Ah, Al, Bh, Bl

    const int t    = threadIdx.x;
    const int lane = t & 63;
    const int wave = t >> 6;
    const int wm   = wave >> 1, wn = wave & 1;
    const int bm0  = blockIdx.y * 128, bn0 = blockIdx.x * 128;

    f32x4 acc[4][4];
#pragma unroll
    for (int i = 0; i < 4; ++i)
#pragma unroll
        for (int j = 0; j < 4; ++j) acc[i][j] = (f32x4){0.f, 0.f, 0.f, 0.f};

    for (int k0 = 0; k0 < K; k0 += 64) {
        __syncthreads();
#pragma unroll
        for (int rep = 0; rep < 16; ++rep) {
            const int tile = rep >> 2;
            const int sig  = (rep & 3) * 256 + t;
            const int row  = sig >> 3;
            const int slot = sig & 7;
            const int slog = slot ^ (row & 7);
            const ushort* src = (tile == 0) ? Ah : (tile == 1) ? Al
                              : (tile == 2) ? Bh : Bl;
            const int rb = (tile < 2) ? bm0 : bn0;
            gload16(src + (size_t)(rb + row) * K + k0 + slog * 8,
                    &ldsT[tile][sig * 8]);
        }
        __syncthreads();

#pragma unroll
        for (int s = 0; s < 2; ++s) {
            b16x8 af[4][2], bf[4][2];
#pragma unroll
            for (int i = 0; i < 4; ++i) {
                const int rA = wm * 64 + i * 16 + (lane & 15);
                const int sA = (s * 4 + (lane >> 4)) ^ (rA & 7);
                af[i][0] = *(const b16x8*)&ldsT[0][rA * 64 + sA * 8];
                af[i][1] = *(const b16x8*)&ldsT[1][rA * 64 + sA * 8];
                const int rB = wn * 64 + i * 16 + (lane & 15);
                const int sB = (s * 4 + (lane >> 4)) ^ (rB & 7);
                bf[i][0] = *(const b16x8*)&ldsT[2][rB * 64 + sB * 8];
                bf[i][1] = *(const b16x8*)&ldsT[3][rB * 64 + sB * 8];
            }
#pragma unroll
            for (int i = 0; i < 4; ++i)
#pragma unroll
                for (int j = 0; j < 4; ++j) {
                    acc[i][j] = __builtin_amdgcn_mfma_f32_16x16x32_bf16(
                        af[i][0], bf[j][0], acc[i][j], 0, 0, 0);
                    acc[i][j] = __builtin_amdgcn_mfma_f32_16x16x32_bf16(
                        af[i][0], bf[j][1], acc[i][j], 0, 0, 0);
                    acc[i][j] = __builtin_amdgcn_mfma_f32_16x16x32_bf16(
                        af[i][1], bf[j][0], acc[i][j], 0, 0, 0);
                }
        }
    }

    // epilogue: bias, Q-scale, split to bf16; V transposed per head
#pragma unroll
    for (int i = 0; i < 4; ++i) {
        const int row = bm0 + wm * 64 + i * 16 + (lane >> 4) * 4;   // s index, %4==0
#pragma unroll
        for (int j = 0; j < 4; ++j) {
            const int col = bn0 + wn * 64 + j * 16 + (lane & 15);
            const float bv = bias[col];
            if (col < 2048) {
                const float sc = (col < 1024) ? 0.125f : 1.0f;
#pragma unroll
                for (int r = 0; r < 4; ++r) {
                    float v = (acc[i][j][r] + bv) * sc;
                    ushort hh, ll;
                    split2(v, &hh, &ll);
                    qkvh[(size_t)(row + r) * 2048 + col] = hh;
                    qkvl[(size_t)(row + r) * 2048 + col] = ll;
                }
            } else {
                const int d = (col - 2048) & 63, hh_ = (col - 2048) >> 6;
                const int b = row >> 11, s = row & 2047;
                ushort4 hv, lv;
                float v0 = acc[i][j][0] + bv, v1 = acc[i][j][1] + bv;
                float v2 = acc[i][j][2] + bv, v3 = acc[i][j][3] + bv;
                split2(v0, &hv.x, &lv.x);
                split2(v1, &hv.y, &lv.y);
                split2(v2, &hv.z, &lv.z);
                split2(v3, &hv.w, &lv.w);
                size_t off = ((size_t)(b * NH + hh_) * 64 + d) * S_LEN + s;
                *(ushort4*)(Vth + off) = hv;
                *(ushort4*)(Vtl + off) = lv;
            }
        }
    }
}

// ---------------------------------------------------------------------------
// Generic split-bf16 GEMM with fp32 output (used for the out-projection).
// ---------------------------------------------------------------------------
__global__ __launch_bounds__(256, 2) void gemm_split_bf16(
    const ushort* __restrict__ Ah, const ushort* __restrict__ Al,
    const ushort* __restrict__ Bh, const ushort* __restrict__ Bl,
    const float* __restrict__ bias, float* __restrict__ C,
    int M, int N, int K)
{
    __shared__ __align__(16) ushort ldsT[4][128 * 64];

    const int t    = threadIdx.x;
    const int lane = t & 63;
    const int wave = t >> 6;
    const int wm   = wave >> 1, wn = wave & 1;
    const int bm0  = blockIdx.y * 128, bn0 = blockIdx.x * 128;

    f32x4 acc[4][4];
#pragma unroll
    for (int i = 0; i < 4; ++i)
#pragma unroll
        for (int j = 0; j < 4; ++j) acc[i][j] = (f32x4){0.f, 0.f, 0.f, 0.f};

    for (int k0 = 0; k0 < K; k0 += 64) {
        __syncthreads();
#pragma unroll
        for (int rep = 0; rep < 16; ++rep) {
            const int tile = rep >> 2;
            const int sig  = (rep & 3) * 256 + t;
            const int row  = sig >> 3;
            const int slot = sig & 7;
            const int slog = slot ^ (row & 7);
            const ushort* src = (tile == 0) ? Ah : (tile == 1) ? Al
                              : (tile == 2) ? Bh : Bl;
            const int rb = (tile < 2) ? bm0 : bn0;
            gload16(src + (size_t)(rb + row) * K + k0 + slog * 8,
                    &ldsT[tile][sig * 8]);
        }
        __syncthreads();

#pragma unroll
        for (int s = 0; s < 2; ++s) {
            b16x8 af[4][2], bf[4][2];
#pragma unroll
            for (int i = 0; i < 4; ++i) {
                const int rA = wm * 64 + i * 16 + (lane & 15);
                const int sA = (s * 4 + (lane >> 4)) ^ (rA & 7);
                af[i][0] = *(const b16x8*)&ldsT[0][rA * 64 + sA * 8];
                af[i][1] = *(const b16x8*)&ldsT[1][rA * 64 + sA * 8];
                const int rB = wn * 64 + i * 16 + (lane & 15);
                const int sB = (s * 4 + (lane >> 4)) ^ (rB & 7);
                bf[i][0] = *(const b16x8*)&ldsT[2][rB * 64 + sB * 8];
                bf[i][1] = *(const b16x8*)&ldsT[3][rB * 64 + sB * 8];
            }
#pragma unroll
            for (int i = 0; i < 4; ++i)
#pragma unroll
                for (int j = 0; j < 4; ++j) {
                    acc[i][j] = __builtin_amdgcn_mfma_f32_16x16x32_bf16(
                        af[i][0], bf[j][0], acc[i][j], 0, 0, 0);
                    acc[i][j] = __builtin_amdgcn_mfma_f32_16x16x32_bf16(
                        af[i][0], bf[j][1], acc[i][j], 0, 0, 0);
                    acc[i][j] = __builtin_amdgcn_mfma_f32_16x16x32_bf16(
                        af[i][1], bf[j][0], acc[i][j], 0, 0, 0);
                }
        }
    }

#pragma unroll
    for (int i = 0; i < 4; ++i) {
        const int row = bm0 + wm * 64 + i * 16 + (lane >> 4) * 4;
#pragma unroll
        for (int j = 0; j < 4; ++j) {
            const int col = bn0 + wn * 64 + j * 16 + (lane & 15);
            const float bv = bias[col];
#pragma unroll
            for (int r = 0; r < 4; ++r)
                C[(size_t)(row + r) * N + col] = acc[i][j][r] + bv;
        }
    }
}

// ---------------------------------------------------------------------------
// MFMA flash attention. Grid (32 qb, 32 bh), 256 thr = 4 waves.
// Wave w owns q-rows w*16..w*16+15. kv-tiles of 64.
// Swapped QK^T: mfma(A=K_tile, B=Q_frag) -> lane holds scores for ONE q
// (q = lane&15) across 16 kv -> in-lane softmax + 2 shuffles.
// Split-bf16 QK^T (3 MFMA), plain-bf16 P, split V (2 MFMA). All LDS b128
// reads XOR-swizzled (slot ^ row&7); staged with pre-swizzled global source.
// LDS 48KB -> 3 blocks/CU.
// ---------------------------------------------------------------------------
__global__ __launch_bounds__(256, 3) void attn_mfma(
    const ushort* __restrict__ qkvh, const ushort* __restrict__ qkvl,
    const ushort* __restrict__ Vth, const ushort* __restrict__ Vtl,
    const float* __restrict__ mask,
    ushort* __restrict__ Yh, ushort* __restrict__ Yl)
{
    __shared__ __align__(16) ushort KV[4][4096];   // Kh, Kl, Vh, Vl tiles [64][64]
    __shared__ __align__(16) ushort Qs[2][4096];   // Q hi/lo; [0] reused as P
    ushort* Ps = &Qs[0][0];

    const int t    = threadIdx.x;
    const int lane = t & 63;
    const int w    = t >> 6;
    const int l15  = lane & 15;
    const int lg   = lane >> 4;
    const int qb   = blockIdx.x;
    const int bh   = blockIdx.y;
    const int b    = bh >> 4, h = bh & 15;

    // ---- stage Q tile (hi/lo), swizzled source -> linear LDS ----
#pragma unroll
    for (int c = 0; c < 4; ++c) {
        int idx = c * 256 + t;
        int buf = idx >> 9, ci = idx & 511, row = ci >> 3, slot = ci & 7;
        const ushort* src = (buf ? qkvl : qkvh)
            + (size_t)(b * S_LEN + qb * 64 + row) * 2048 + h * 64
            + (slot ^ (row & 7)) * 8;
        gload16(src, &Qs[buf][ci * 8]);
    }
    __syncthreads();

    // ---- hoist Q B-frags to registers ----
    b16x8 qf[2][2];
    {
        const int qrow = w * 16 + l15;
        const int sw   = qrow & 7;
#pragma unroll
        for (int ks = 0; ks < 2; ++ks) {
            qf[ks][0] = *(const b16x8*)&Qs[0][qrow * 64 + (((ks * 4 + lg) ^ sw) * 8)];
            qf[ks][1] = *(const b16x8*)&Qs[1][qrow * 64 + (((ks * 4 + lg) ^ sw) * 8)];
        }
    }
    __syncthreads();   // Q reads done before Ps overwrite

    float m_run = -3.0e38f, l_run = 0.0f;
    f32x4 accO[4];
#pragma unroll
    for (int fi = 0; fi < 4; ++fi) accO[fi] = (f32x4){0.f, 0.f, 0.f, 0.f};

    const float* Mrow = mask + (size_t)b * S_LEN * S_LEN
                      + (size_t)(qb * 64 + w * 16 + l15) * S_LEN;
    const int prow = w * 16 + l15;
    const int psw  = prow & 7;

    for (int kv0 = 0; kv0 < S_LEN; kv0 += 64) {
        __syncthreads();   // previous tile's K/V/P reads complete
#pragma unroll
        for (int c = 0; c < 8; ++c) {
            int idx = c * 256 + t;
            int sel = idx >> 9, ci = idx & 511, row = ci >> 3, slot = ci & 7;
            int sc = (slot ^ (row & 7)) * 8;
            const ushort* src;
            if (sel == 0)
                src = qkvh + (size_t)(b * S_LEN + kv0 + row) * 2048 + 1024 + h * 64 + sc;
            else if (sel == 1)
                src = qkvl + (size_t)(b * S_LEN + kv0 + row) * 2048 + 1024 + h * 64 + sc;
            else if (sel == 2)
                src = Vth + (size_t)((b * NH + h) * 64 + row) * S_LEN + kv0 + sc;
            else
                src = Vtl + (size_t)((b * NH + h) * 64 + row) * S_LEN + kv0 + sc;
            gload16(src, &KV[sel][ci * 8]);
        }
        __syncthreads();

        // ---- scores: C[kv 64][q 16] via mfma(K, Q); init with mask*(-1e4) ----
        f32x4 c4[4];
#pragma unroll
        for (int fi = 0; fi < 4; ++fi) {
            float4 mv = *(const float4*)(Mrow + kv0 + fi * 16 + lg * 4);
            c4[fi][0] = mv.x * -10000.f;
            c4[fi][1] = mv.y * -10000.f;
            c4[fi][2] = mv.z * -10000.f;
            c4[fi][3] = mv.w * -10000.f;
        }
#pragma unroll
        for (int fi = 0; fi < 4; ++fi) {
            const int krow = fi * 16 + l15;
            const int sw   = krow & 7;
            b16x8 kh0 = *(const b16x8*)&KV[0][krow * 64 + (((0 + lg) ^ sw) * 8)];
            b16x8 kh1 = *(const b16x8*)&KV[0][krow * 64 + (((4 + lg) ^ sw) * 8)];
            b16x8 kl0 = *(const b16x8*)&KV[1][krow * 64 + (((0 + lg) ^ sw) * 8)];
            b16x8 kl1 = *(const b16x8*)&KV[1][krow * 64 + (((4 + lg) ^ sw) * 8)];
            c4[fi] = __builtin_amdgcn_mfma_f32_16x16x32_bf16(kh0, qf[0][0], c4[fi], 0, 0, 0);
            c4[fi] = __builtin_amdgcn_mfma_f32_16x16x32_bf16(kh0, qf[0][1], c4[fi], 0, 0, 0);
            c4[fi] = __builtin_amdgcn_mfma_f32_16x16x32_bf16(kl0, qf[0][0], c4[fi], 0, 0, 0);
            c4[fi] = __builtin_amdgcn_mfma_f32_16x16x32_bf16(kh1, qf[1][0], c4[fi], 0, 0, 0);
            c4[fi] = __builtin_amdgcn_mfma_f32_16x16x32_bf16(kh1, qf[1][1], c4[fi], 0, 0, 0);
            c4[fi] = __builtin_amdgcn_mfma_f32_16x16x32_bf16(kl1, qf[1][0], c4[fi], 0, 0, 0);
        }

        // ---- online softmax (lane's q = l15; replicated across lg) ----
        float mt = fmaxf(fmaxf(fmaxf(c4[0][0], c4[0][1]), fmaxf(c4[0][2], c4[0][3])),
                         fmaxf(fmaxf(c4[1][0], c4[1][1]), fmaxf(c4[1][2], c4[1][3])));
        mt = fmaxf(mt, fmaxf(fmaxf(fmaxf(c4[2][0], c4[2][1]), fmaxf(c4[2][2], c4[2][3])),
                             fmaxf(fmaxf(c4[3][0], c4[3][1]), fmaxf(c4[3][2], c4[3][3]))));
        mt = fmaxf(mt, __shfl_xor(mt, 16));
        mt = fmaxf(mt, __shfl_xor(mt, 32));
        const float mn   = fmaxf(m_run, mt);
        const float corr = __expf(m_run - mn);
        float p[4][4];
        float ps = 0.f;
#pragma unroll
        for (int fi = 0; fi < 4; ++fi)
#pragma unroll
            for (int r = 0; r < 4; ++r) {
                p[fi][r] = __expf(c4[fi][r] - mn);
                ps += p[fi][r];
            }
        ps += __shfl_xor(ps, 16);
        ps += __shfl_xor(ps, 32);
        l_run = l_run * corr + ps;
        m_run = mn;

        // ---- write P (bf16) to LDS, swizzled; intra-wave rows only ----
#pragma unroll
        for (int fi = 0; fi < 4; ++fi) {
            const int kvb  = fi * 16 + lg * 4;
            const int slot = kvb >> 3;
            ushort4 pv;
            pv.x = bf16_rne(p[fi][0]);
            pv.y = bf16_rne(p[fi][1]);
            pv.z = bf16_rne(p[fi][2]);
            pv.w = bf16_rne(p[fi][3]);
            *(ushort4*)&Ps[prow * 64 + ((slot ^ psw) * 16) / 2 + (kvb & 7)] = pv;
        }

        // ---- rescale running O ----
        float cr0 = __shfl(corr, lg * 4 + 0);
        float cr1 = __shfl(corr, lg * 4 + 1);
        float cr2 = __shfl(corr, lg * 4 + 2);
        float cr3 = __shfl(corr, lg * 4 + 3);
#pragma unroll
        for (int fi = 0; fi < 4; ++fi) {
            accO[fi][0] *= cr0; accO[fi][1] *= cr1;
            accO[fi][2] *= cr2; accO[fi][3] *= cr3;
        }

        // ---- PV: accO[q 16][d 64] += P @ V ----
        b16x8 pf0 = *(const b16x8*)&Ps[prow * 64 + (((0 + lg) ^ psw) * 8)];
        b16x8 pf1 = *(const b16x8*)&Ps[prow * 64 + (((4 + lg) ^ psw) * 8)];
#pragma unroll
        for (int fi = 0; fi < 4; ++fi) {
            const int vrow = fi * 16 + l15;
            const int sw   = vrow & 7;
            b16x8 vh0 = *(const b16x8*)&KV[2][vrow * 64 + (((0 + lg) ^ sw) * 8)];
            b16x8 vh1 = *(const b16x8*)&KV[2][vrow * 64 + (((4 + lg) ^ sw) * 8)];
            b16x8 vl0 = *(const b16x8*)&KV[3][vrow * 64 + (((0 + lg) ^ sw) * 8)];
            b16x8 vl1 = *(const b16x8*)&KV[3][vrow * 64 + (((4 + lg) ^ sw) * 8)];
            accO[fi] = __builtin_amdgcn_mfma_f32_16x16x32_bf16(pf0, vh0, accO[fi], 0, 0, 0);
            accO[fi] = __builtin_amdgcn_mfma_f32_16x16x32_bf16(pf0, vl0, accO[fi], 0, 0, 0);
            accO[fi] = __builtin_amdgcn_mfma_f32_16x16x32_bf16(pf1, vh1, accO[fi], 0, 0, 0);
            accO[fi] = __builtin_amdgcn_mfma_f32_16x16x32_bf16(pf1, vl1, accO[fi], 0, 0, 0);
        }
    }

    // ---- epilogue: normalize, split to bf16 hi/lo ----
    const float il = 1.0f / l_run;
    float ir[4];
    ir[0] = __shfl(il, lg * 4 + 0);
    ir[1] = __shfl(il, lg * 4 + 1);
    ir[2] = __shfl(il, lg * 4 + 2);
    ir[3] = __shfl(il, lg * 4 + 3);
#pragma unroll
    for (int fi = 0; fi < 4; ++fi)
#pragma unroll
        for (int r = 0; r < 4; ++r) {
            float y = accO[fi][r] * ir[r];
            ushort hy, ly;
            split2(y, &hy, &ly);
            size_t off = (size_t)(b * S_LEN + qb * 64 + w * 16 + lg * 4 + r) * EMB
                       + h * 64 + fi * 16 + l15;
            Yh[off] = hy;
            Yl[off] = ly;
        }
}

// ---------------------------------------------------------------------------
extern "C" void kernel_launch(void* const* d_in, const int* in_sizes, int n_in,
                              void* d_out, int out_size, void* d_ws, size_t ws_size,
                              hipStream_t stream)
{
    const float* x     = (const float*)d_in[0];
    const float* mask  = (const float*)d_in[1];
    const float* w_in  = (const float*)d_in[2];
    const float* b_in  = (const float*)d_in[3];
    const float* w_out = (const float*)d_in[4];
    const float* b_out = (const float*)d_in[5];
    float* out = (float*)d_out;

    // workspace layout (80 MB total, same footprint as round 4):
    char* ws = (char*)d_ws;
    ushort* qkvh = (ushort*)(ws + 0);            // [4096][2048] Q,K hi
    ushort* qkvl = (ushort*)(ws + 16777216);     // [4096][2048] Q,K lo
    ushort* Vth  = (ushort*)(ws + 33554432);     // [32][64][2048] V^T hi
    ushort* Vtl  = (ushort*)(ws + 41943040);     // [32][64][2048] V^T lo
    ushort* Xh   = (ushort*)(ws + 50331648);     // [4096][1024] X hi (reused as Y hi)
    ushort* Xl   = (ushort*)(ws + 58720256);     // [4096][1024] X lo (reused as Y lo)
    ushort* Wih  = (ushort*)(ws + 67108864);     // [3072][1024] hi
    ushort* Wil  = (ushort*)(ws + 73400320);
    ushort* Woh  = (ushort*)(ws + 79691776);     // [1024][1024] hi
    ushort* Wol  = (ushort*)(ws + 81788928);
    ushort* Yh = Xh;   // X dead after QKV projection
    ushort* Yl = Xl;

    // 0) split fp32 -> bf16 hi/lo
    split_f32_kernel<<<4096, 256, 0, stream>>>((const float4*)x,
        (ushort4*)Xh, (ushort4*)Xl, 1048576);
    split_f32_kernel<<<3072, 256, 0, stream>>>((const float4*)w_in,
        (ushort4*)Wih, (ushort4*)Wil, 786432);
    split_f32_kernel<<<1024, 256, 0, stream>>>((const float4*)w_out,
        (ushort4*)Woh, (ushort4*)Wol, 262144);

    // 1) QKV projection -> pre-split bf16 Q,K (Q scaled 1/8) + transposed V
    gemm_qkv<<<dim3(E3 / 128, 4096 / 128), 256, 0, stream>>>(
        Xh, Xl, Wih, Wil, b_in, qkvh, qkvl, Vth, Vtl);

    // 2) MFMA flash attention -> Y (split bf16)
    attn_mfma<<<dim3(S_LEN / 64, 2 * NH), 256, 0, stream>>>(
        qkvh, qkvl, Vth, Vtl, mask, Yh, Yl);

    // 3) out projection: out = Y @ W_out^T + b_out (fp32 out)
    gemm_split_bf16<<<dim3(EMB / 128, 4096 / 128), 256, 0, stream>>>(
        Yh, Yl, Woh, Wol, b_out, out, 4096, EMB, EMB);
}

// Round 10
// 385.477 us; speedup vs baseline: 3.4178x; 1.0168x over previous
//
#include <hip/hip_runtime.h>
#include <cstdint>
#include <cstddef>

#define S_LEN 2048
#define EMB   1024
#define NH    16
#define HD    64
#define E3    3072   // 3*EMB

typedef __attribute__((ext_vector_type(8))) short b16x8;   // 8 bf16 = 4 VGPR (MFMA A/B frag)
typedef __attribute__((ext_vector_type(4))) float f32x4;   // MFMA C/D frag

// ---- bf16 split helpers (RNE via bit ops; data is finite) -------------------
__device__ __forceinline__ ushort bf16_rne(float f) {
    uint32_t u = __float_as_uint(f);
    uint32_t r = (u + 0x7FFFu + ((u >> 16) & 1u)) >> 16;
    return (ushort)r;
}
__device__ __forceinline__ void split2(float f, ushort* h, ushort* l) {
    ushort hh = bf16_rne(f);
    *h = hh;
    float rem = f - __uint_as_float(((uint32_t)hh) << 16);
    *l = bf16_rne(rem);
}

// ---- fp32 -> (bf16 hi, bf16 lo) elementwise ---------------------------------
__global__ __launch_bounds__(256) void split_f32_kernel(
    const float4* __restrict__ src, ushort4* __restrict__ h,
    ushort4* __restrict__ l, int n4)
{
    int i = blockIdx.x * 256 + threadIdx.x;
    if (i >= n4) return;
    float4 v = src[i];
    ushort4 hv, lv;
    split2(v.x, &hv.x, &lv.x);
    split2(v.y, &hv.y, &lv.y);
    split2(v.z, &hv.z, &lv.z);
    split2(v.w, &hv.w, &lv.w);
    h[i] = hv; l[i] = lv;
}

// ---- async 16B global->LDS --------------------------------------------------
__device__ __forceinline__ void gload16(const void* g, void* lds) {
    __builtin_amdgcn_global_load_lds(
        (const __attribute__((address_space(1))) uint32_t*)g,
        (__attribute__((address_space(3))) uint32_t*)lds, 16, 0, 0);
}

// ---------------------------------------------------------------------------
// QKV projection GEMM (split-bf16, 3-MFMA): qkv = X @ Win^T + b_in.
// M=4096, N=3072, K=1024. Epilogue: Q cols (<1024) scaled 1/8, Q,K written as
// split bf16 row-major [4096][2048]; V cols written TRANSPOSED per head:
// Vt[b*16+h][d][s] (split bf16) so attention's PV B-operand is kv-contiguous.
// ---------------------------------------------------------------------------
__global__ __launch_bounds__(256, 2) void gemm_qkv(
    const ushort* __restrict__ Ah, const ushort* __restrict__ Al,
    const ushort* __restrict__ Bh, const ushort* __restrict__ Bl,
    const float* __restrict__ bias,
    ushort* __restrict__ qkvh, ushort* __restrict__ qkvl,
    ushort* __restrict__ Vth, ushort* __restrict__ Vtl)
{
    const int K = 1024;
    __shared__ __align__(16) ushort ldsT[4][128 * 64];   // Ah, Al, Bh, Bl

    const int t    = threadIdx.x;
    const int lane = t & 63;
    const int wave = t >> 6;
    const int wm   = wave >> 1, wn = wave & 1;
    const int bm0  = blockIdx.y * 128, bn0 = blockIdx.x * 128;

    f32x4 acc[4][4];
#pragma unroll
    for (int i = 0; i < 4; ++i)
#pragma unroll
        for (int j = 0; j < 4; ++j) acc[i][j] = (f32x4){0.f, 0.f, 0.f, 0.f};

    for (int k0 = 0; k0 < K; k0 += 64) {
        __syncthreads();
#pragma unroll
        for (int rep = 0; rep < 16; ++rep) {
            const int tile = rep >> 2;
            const int sig  = (rep & 3) * 256 + t;
            const int row  = sig >> 3;
            const int slot = sig & 7;
            const int slog = slot ^ (row & 7);
            const ushort* src = (tile == 0) ? Ah : (tile == 1) ? Al
                              : (tile == 2) ? Bh : Bl;
            const int rb = (tile < 2) ? bm0 : bn0;
            gload16(src + (size_t)(rb + row) * K + k0 + slog * 8,
                    &ldsT[tile][sig * 8]);
        }
        __syncthreads();

#pragma unroll
        for (int s = 0; s < 2; ++s) {
            b16x8 af[4][2], bf[4][2];
#pragma unroll
            for (int i = 0; i < 4; ++i) {
                const int rA = wm * 64 + i * 16 + (lane & 15);
                const int sA = (s * 4 + (lane >> 4)) ^ (rA & 7);
                af[i][0] = *(const b16x8*)&ldsT[0][rA * 64 + sA * 8];
                af[i][1] = *(const b16x8*)&ldsT[1][rA * 64 + sA * 8];
                const int rB = wn * 64 + i * 16 + (lane & 15);
                const int sB = (s * 4 + (lane >> 4)) ^ (rB & 7);
                bf[i][0] = *(const b16x8*)&ldsT[2][rB * 64 + sB * 8];
                bf[i][1] = *(const b16x8*)&ldsT[3][rB * 64 + sB * 8];
            }
#pragma unroll
            for (int i = 0; i < 4; ++i)
#pragma unroll
                for (int j = 0; j < 4; ++j) {
                    acc[i][j] = __builtin_amdgcn_mfma_f32_16x16x32_bf16(
                        af[i][0], bf[j][0], acc[i][j], 0, 0, 0);
                    acc[i][j] = __builtin_amdgcn_mfma_f32_16x16x32_bf16(
                        af[i][0], bf[j][1], acc[i][j], 0, 0, 0);
                    acc[i][j] = __builtin_amdgcn_mfma_f32_16x16x32_bf16(
                        af[i][1], bf[j][0], acc[i][j], 0, 0, 0);
                }
        }
    }

    // epilogue: bias, Q-scale, split to bf16; V transposed per head
#pragma unroll
    for (int i = 0; i < 4; ++i) {
        const int row = bm0 + wm * 64 + i * 16 + (lane >> 4) * 4;   // s index, %4==0
#pragma unroll
        for (int j = 0; j < 4; ++j) {
            const int col = bn0 + wn * 64 + j * 16 + (lane & 15);
            const float bv = bias[col];
            if (col < 2048) {
                const float sc = (col < 1024) ? 0.125f : 1.0f;
#pragma unroll
                for (int r = 0; r < 4; ++r) {
                    float v = (acc[i][j][r] + bv) * sc;
                    ushort hh, ll;
                    split2(v, &hh, &ll);
                    qkvh[(size_t)(row + r) * 2048 + col] = hh;
                    qkvl[(size_t)(row + r) * 2048 + col] = ll;
                }
            } else {
                const int d = (col - 2048) & 63, hh_ = (col - 2048) >> 6;
                const int b = row >> 11, s = row & 2047;
                ushort4 hv, lv;
                float v0 = acc[i][j][0] + bv, v1 = acc[i][j][1] + bv;
                float v2 = acc[i][j][2] + bv, v3 = acc[i][j][3] + bv;
                split2(v0, &hv.x, &lv.x);
                split2(v1, &hv.y, &lv.y);
                split2(v2, &hv.z, &lv.z);
                split2(v3, &hv.w, &lv.w);
                size_t off = ((size_t)(b * NH + hh_) * 64 + d) * S_LEN + s;
                *(ushort4*)(Vth + off) = hv;
                *(ushort4*)(Vtl + off) = lv;
            }
        }
    }
}

// ---------------------------------------------------------------------------
// Generic split-bf16 GEMM with fp32 output (used for the out-projection).
// ---------------------------------------------------------------------------
__global__ __launch_bounds__(256, 2) void gemm_split_bf16(
    const ushort* __restrict__ Ah, const ushort* __restrict__ Al,
    const ushort* __restrict__ Bh, const ushort* __restrict__ Bl,
    const float* __restrict__ bias, float* __restrict__ C,
    int M, int N, int K)
{
    __shared__ __align__(16) ushort ldsT[4][128 * 64];

    const int t    = threadIdx.x;
    const int lane = t & 63;
    const int wave = t >> 6;
    const int wm   = wave >> 1, wn = wave & 1;
    const int bm0  = blockIdx.y * 128, bn0 = blockIdx.x * 128;

    f32x4 acc[4][4];
#pragma unroll
    for (int i = 0; i < 4; ++i)
#pragma unroll
        for (int j = 0; j < 4; ++j) acc[i][j] = (f32x4){0.f, 0.f, 0.f, 0.f};

    for (int k0 = 0; k0 < K; k0 += 64) {
        __syncthreads();
#pragma unroll
        for (int rep = 0; rep < 16; ++rep) {
            const int tile = rep >> 2;
            const int sig  = (rep & 3) * 256 + t;
            const int row  = sig >> 3;
            const int slot = sig & 7;
            const int slog = slot ^ (row & 7);
            const ushort* src = (tile == 0) ? Ah : (tile == 1) ? Al
                              : (tile == 2) ? Bh : Bl;
            const int rb = (tile < 2) ? bm0 : bn0;
            gload16(src + (size_t)(rb + row) * K + k0 + slog * 8,
                    &ldsT[tile][sig * 8]);
        }
        __syncthreads();

#pragma unroll
        for (int s = 0; s < 2; ++s) {
            b16x8 af[4][2], bf[4][2];
#pragma unroll
            for (int i = 0; i < 4; ++i) {
                const int rA = wm * 64 + i * 16 + (lane & 15);
                const int sA = (s * 4 + (lane >> 4)) ^ (rA & 7);
                af[i][0] = *(const b16x8*)&ldsT[0][rA * 64 + sA * 8];
                af[i][1] = *(const b16x8*)&ldsT[1][rA * 64 + sA * 8];
                const int rB = wn * 64 + i * 16 + (lane & 15);
                const int sB = (s * 4 + (lane >> 4)) ^ (rB & 7);
                bf[i][0] = *(const b16x8*)&ldsT[2][rB * 64 + sB * 8];
                bf[i][1] = *(const b16x8*)&ldsT[3][rB * 64 + sB * 8];
            }
#pragma unroll
            for (int i = 0; i < 4; ++i)
#pragma unroll
                for (int j = 0; j < 4; ++j) {
                    acc[i][j] = __builtin_amdgcn_mfma_f32_16x16x32_bf16(
                        af[i][0], bf[j][0], acc[i][j], 0, 0, 0);
                    acc[i][j] = __builtin_amdgcn_mfma_f32_16x16x32_bf16(
                        af[i][0], bf[j][1], acc[i][j], 0, 0, 0);
                    acc[i][j] = __builtin_amdgcn_mfma_f32_16x16x32_bf16(
                        af[i][1], bf[j][0], acc[i][j], 0, 0, 0);
                }
        }
    }

#pragma unroll
    for (int i = 0; i < 4; ++i) {
        const int row = bm0 + wm * 64 + i * 16 + (lane >> 4) * 4;
#pragma unroll
        for (int j = 0; j < 4; ++j) {
            const int col = bn0 + wn * 64 + j * 16 + (lane & 15);
            const float bv = bias[col];
#pragma unroll
            for (int r = 0; r < 4; ++r)
                C[(size_t)(row + r) * N + col] = acc[i][j][r] + bv;
        }
    }
}

// ---- stage one K/V tile (4 matrices x [64][64] bf16) into LDS --------------
__device__ __forceinline__ void stage_kv_tile(
    const ushort* __restrict__ qkvh, const ushort* __restrict__ qkvl,
    const ushort* __restrict__ Vth, const ushort* __restrict__ Vtl,
    int b, int h, int kv0, int t, ushort* dst /* [4][4096] */)
{
#pragma unroll
    for (int c = 0; c < 8; ++c) {
        int idx = c * 256 + t;
        int sel = idx >> 9, ci = idx & 511, row = ci >> 3, slot = ci & 7;
        int sc = (slot ^ (row & 7)) * 8;
        const ushort* src;
        if (sel == 0)
            src = qkvh + (size_t)(b * S_LEN + kv0 + row) * 2048 + 1024 + h * 64 + sc;
        else if (sel == 1)
            src = qkvl + (size_t)(b * S_LEN + kv0 + row) * 2048 + 1024 + h * 64 + sc;
        else if (sel == 2)
            src = Vth + (size_t)((b * NH + h) * 64 + row) * S_LEN + kv0 + sc;
        else
            src = Vtl + (size_t)((b * NH + h) * 64 + row) * S_LEN + kv0 + sc;
        gload16(src, dst + sel * 4096 + ci * 8);
    }
}

// ---------------------------------------------------------------------------
// MFMA flash attention, double-buffered (issue-early/wait-late).
// Grid 1024 blocks, 256 thr = 4 waves; wave w owns q-rows w*16..+15.
// Per kv-tile: STAGE(next tile, async) -> compute(cur) -> syncthreads (the
// compiler's vmcnt(0)+lgkmcnt(0) drain before s_barrier is the wait-late
// point; staging latency hides under ~40 MFMA + softmax). One barrier/tile.
// XCD-aware remap: each XCD's L2 gets 4 complete (b,h) K/V working sets.
// LDS 80KB -> 2 blocks/CU.
// ---------------------------------------------------------------------------
__global__ __launch_bounds__(256, 2) void attn_mfma(
    const ushort* __restrict__ qkvh, const ushort* __restrict__ qkvl,
    const ushort* __restrict__ Vth, const ushort* __restrict__ Vtl,
    const float* __restrict__ mask,
    ushort* __restrict__ Yh, ushort* __restrict__ Yl)
{
    __shared__ __align__(16) ushort KVb[2][4][4096];   // dbuf x {Kh,Kl,Vh,Vl} [64][64]
    __shared__ __align__(16) ushort Qs[2][4096];       // Q hi/lo; [0] reused as P
    ushort* Ps = &Qs[0][0];

    const int t    = threadIdx.x;
    const int lane = t & 63;
    const int w    = t >> 6;
    const int l15  = lane & 15;
    const int lg   = lane >> 4;

    // XCD-aware remap: dispatch id d -> work (bh=wy, qb=wx); XCD k = d%8 gets
    // works wy in {4k..4k+3} (4 heads' K/V = 4MB = one L2).
    const int d  = blockIdx.y * 32 + blockIdx.x;
    const int wy = 4 * (d & 7) + ((d >> 3) >> 5);
    const int qb = (d >> 3) & 31;
    const int b  = wy >> 4, h = wy & 15;

    // ---- stage Q tile (hi/lo), swizzled source -> linear LDS ----
#pragma unroll
    for (int c = 0; c < 4; ++c) {
        int idx = c * 256 + t;
        int buf = idx >> 9, ci = idx & 511, row = ci >> 3, slot = ci & 7;
        const ushort* src = (buf ? qkvl : qkvh)
            + (size_t)(b * S_LEN + qb * 64 + row) * 2048 + h * 64
            + (slot ^ (row & 7)) * 8;
        gload16(src, &Qs[buf][ci * 8]);
    }
    // ---- stage K/V tile 0 into buffer 0 ----
    stage_kv_tile(qkvh, qkvl, Vth, Vtl, b, h, 0, t, &KVb[0][0][0]);

    const float* Mrow = mask + (size_t)b * S_LEN * S_LEN
                      + (size_t)(qb * 64 + w * 16 + l15) * S_LEN;
    // prefetch tile 0's mask rows into registers
    float4 mcur[4], mnext[4];
#pragma unroll
    for (int fi = 0; fi < 4; ++fi)
        mcur[fi] = *(const float4*)(Mrow + fi * 16 + lg * 4);

    __syncthreads();   // Q + tile0 staging complete, visible to all waves

    // ---- hoist Q B-frags to registers (intra-wave rows only) ----
    b16x8 qf[2][2];
    {
        const int qrow = w * 16 + l15;
        const int sw   = qrow & 7;
#pragma unroll
        for (int ks = 0; ks < 2; ++ks) {
            qf[ks][0] = *(const b16x8*)&Qs[0][qrow * 64 + (((ks * 4 + lg) ^ sw) * 8)];
            qf[ks][1] = *(const b16x8*)&Qs[1][qrow * 64 + (((ks * 4 + lg) ^ sw) * 8)];
        }
    }
    __syncthreads();   // safety: Q reads done before Ps (=Qs[0]) overwrite

    float m_run = -3.0e38f, l_run = 0.0f;
    f32x4 accO[4];
#pragma unroll
    for (int fi = 0; fi < 4; ++fi) accO[fi] = (f32x4){0.f, 0.f, 0.f, 0.f};

    const int prow = w * 16 + l15;
    const int psw  = prow & 7;

    int buf = 0;
    for (int kv0 = 0; kv0 < S_LEN; kv0 += 64) {
        const bool notlast = (kv0 + 64 < S_LEN);
        // ---- issue next tile's staging + mask prefetch EARLY ----
        if (notlast) {
            stage_kv_tile(qkvh, qkvl, Vth, Vtl, b, h, kv0 + 64, t,
                          &KVb[buf ^ 1][0][0]);
#pragma unroll
            for (int fi = 0; fi < 4; ++fi)
                mnext[fi] = *(const float4*)(Mrow + kv0 + 64 + fi * 16 + lg * 4);
        }
        const ushort* Kh = &KVb[buf][0][0];
        const ushort* Kl = &KVb[buf][1][0];
        const ushort* Vh = &KVb[buf][2][0];
        const ushort* Vl = &KVb[buf][3][0];

        // ---- scores: C[kv 64][q 16] via mfma(K, Q); init with mask*(-1e4) ----
        f32x4 c4[4];
#pragma unroll
        for (int fi = 0; fi < 4; ++fi) {
            c4[fi][0] = mcur[fi].x * -10000.f;
            c4[fi][1] = mcur[fi].y * -10000.f;
            c4[fi][2] = mcur[fi].z * -10000.f;
            c4[fi][3] = mcur[fi].w * -10000.f;
        }
#pragma unroll
        for (int fi = 0; fi < 4; ++fi) {
            const int krow = fi * 16 + l15;
            const int sw   = krow & 7;
            b16x8 kh0 = *(const b16x8*)&Kh[krow * 64 + (((0 + lg) ^ sw) * 8)];
            b16x8 kh1 = *(const b16x8*)&Kh[krow * 64 + (((4 + lg) ^ sw) * 8)];
            b16x8 kl0 = *(const b16x8*)&Kl[krow * 64 + (((0 + lg) ^ sw) * 8)];
            b16x8 kl1 = *(const b16x8*)&Kl[krow * 64 + (((4 + lg) ^ sw) * 8)];
            c4[fi] = __builtin_amdgcn_mfma_f32_16x16x32_bf16(kh0, qf[0][0], c4[fi], 0, 0, 0);
            c4[fi] = __builtin_amdgcn_mfma_f32_16x16x32_bf16(kh0, qf[0][1], c4[fi], 0, 0, 0);
            c4[fi] = __builtin_amdgcn_mfma_f32_16x16x32_bf16(kl0, qf[0][0], c4[fi], 0, 0, 0);
            c4[fi] = __builtin_amdgcn_mfma_f32_16x16x32_bf16(kh1, qf[1][0], c4[fi], 0, 0, 0);
            c4[fi] = __builtin_amdgcn_mfma_f32_16x16x32_bf16(kh1, qf[1][1], c4[fi], 0, 0, 0);
            c4[fi] = __builtin_amdgcn_mfma_f32_16x16x32_bf16(kl1, qf[1][0], c4[fi], 0, 0, 0);
        }

        // ---- online softmax (lane's q = l15; replicated across lg) ----
        float mt = fmaxf(fmaxf(fmaxf(c4[0][0], c4[0][1]), fmaxf(c4[0][2], c4[0][3])),
                         fmaxf(fmaxf(c4[1][0], c4[1][1]), fmaxf(c4[1][2], c4[1][3])));
        mt = fmaxf(mt, fmaxf(fmaxf(fmaxf(c4[2][0], c4[2][1]), fmaxf(c4[2][2], c4[2][3])),
                             fmaxf(fmaxf(c4[3][0], c4[3][1]), fmaxf(c4[3][2], c4[3][3]))));
        mt = fmaxf(mt, __shfl_xor(mt, 16));
        mt = fmaxf(mt, __shfl_xor(mt, 32));
        const float mn   = fmaxf(m_run, mt);
        const float corr = __expf(m_run - mn);
        float p[4][4];
        float ps = 0.f;
#pragma unroll
        for (int fi = 0; fi < 4; ++fi)
#pragma unroll
            for (int r = 0; r < 4; ++r) {
                p[fi][r] = __expf(c4[fi][r] - mn);
                ps += p[fi][r];
            }
        ps += __shfl_xor(ps, 16);
        ps += __shfl_xor(ps, 32);
        l_run = l_run * corr + ps;
        m_run = mn;

        // ---- write P (bf16) to LDS, swizzled; intra-wave rows only ----
#pragma unroll
        for (int fi = 0; fi < 4; ++fi) {
            const int kvb  = fi * 16 + lg * 4;
            const int slot = kvb >> 3;
            ushort4 pv;
            pv.x = bf16_rne(p[fi][0]);
            pv.y = bf16_rne(p[fi][1]);
            pv.z = bf16_rne(p[fi][2]);
            pv.w = bf16_rne(p[fi][3]);
            *(ushort4*)&Ps[prow * 64 + ((slot ^ psw) * 16) / 2 + (kvb & 7)] = pv;
        }

        // ---- rescale running O ----
        float cr0 = __shfl(corr, lg * 4 + 0);
        float cr1 = __shfl(corr, lg * 4 + 1);
        float cr2 = __shfl(corr, lg * 4 + 2);
        float cr3 = __shfl(corr, lg * 4 + 3);
#pragma unroll
        for (int fi = 0; fi < 4; ++fi) {
            accO[fi][0] *= cr0; accO[fi][1] *= cr1;
            accO[fi][2] *= cr2; accO[fi][3] *= cr3;
        }

        // ---- PV: accO[q 16][d 64] += P @ V ----
        b16x8 pf0 = *(const b16x8*)&Ps[prow * 64 + (((0 + lg) ^ psw) * 8)];
        b16x8 pf1 = *(const b16x8*)&Ps[prow * 64 + (((4 + lg) ^ psw) * 8)];
#pragma unroll
        for (int fi = 0; fi < 4; ++fi) {
            const int vrow = fi * 16 + l15;
            const int sw   = vrow & 7;
            b16x8 vh0 = *(const b16x8*)&Vh[vrow * 64 + (((0 + lg) ^ sw) * 8)];
            b16x8 vh1 = *(const b16x8*)&Vh[vrow * 64 + (((4 + lg) ^ sw) * 8)];
            b16x8 vl0 = *(const b16x8*)&Vl[vrow * 64 + (((0 + lg) ^ sw) * 8)];
            b16x8 vl1 = *(const b16x8*)&Vl[vrow * 64 + (((4 + lg) ^ sw) * 8)];
            accO[fi] = __builtin_amdgcn_mfma_f32_16x16x32_bf16(pf0, vh0, accO[fi], 0, 0, 0);
            accO[fi] = __builtin_amdgcn_mfma_f32_16x16x32_bf16(pf0, vl0, accO[fi], 0, 0, 0);
            accO[fi] = __builtin_amdgcn_mfma_f32_16x16x32_bf16(pf1, vh1, accO[fi], 0, 0, 0);
            accO[fi] = __builtin_amdgcn_mfma_f32_16x16x32_bf16(pf1, vl1, accO[fi], 0, 0, 0);
        }

        // rotate mask prefetch regs
        if (notlast) {
#pragma unroll
            for (int fi = 0; fi < 4; ++fi) mcur[fi] = mnext[fi];
        }

        // wait-late: compiler emits vmcnt(0) lgkmcnt(0) before s_barrier --
        // drains the staging issued at the TOP of this iteration (latency
        // hidden under the 40 MFMA + softmax above), then flips buffers.
        __syncthreads();
        buf ^= 1;
    }

    // ---- epilogue: normalize, split to bf16 hi/lo ----
    const float il = 1.0f / l_run;
    float ir[4];
    ir[0] = __shfl(il, lg * 4 + 0);
    ir[1] = __shfl(il, lg * 4 + 1);
    ir[2] = __shfl(il, lg * 4 + 2);
    ir[3] = __shfl(il, lg * 4 + 3);
#pragma unroll
    for (int fi = 0; fi < 4; ++fi)
#pragma unroll
        for (int r = 0; r < 4; ++r) {
            float y = accO[fi][r] * ir[r];
            ushort hy, ly;
            split2(y, &hy, &ly);
            size_t off = (size_t)(b * S_LEN + qb * 64 + w * 16 + lg * 4 + r) * EMB
                       + h * 64 + fi * 16 + l15;
            Yh[off] = hy;
            Yl[off] = ly;
        }
}

// ---------------------------------------------------------------------------
extern "C" void kernel_launch(void* const* d_in, const int* in_sizes, int n_in,
                              void* d_out, int out_size, void* d_ws, size_t ws_size,
                              hipStream_t stream)
{
    const float* x     = (const float*)d_in[0];
    const float* mask  = (const float*)d_in[1];
    const float* w_in  = (const float*)d_in[2];
    const float* b_in  = (const float*)d_in[3];
    const float* w_out = (const float*)d_in[4];
    const float* b_out = (const float*)d_in[5];
    float* out = (float*)d_out;

    // workspace layout (80 MB total):
    char* ws = (char*)d_ws;
    ushort* qkvh = (ushort*)(ws + 0);            // [4096][2048] Q,K hi
    ushort* qkvl = (ushort*)(ws + 16777216);     // [4096][2048] Q,K lo
    ushort* Vth  = (ushort*)(ws + 33554432);     // [32][64][2048] V^T hi
    ushort* Vtl  = (ushort*)(ws + 41943040);     // [32][64][2048] V^T lo
    ushort* Xh   = (ushort*)(ws + 50331648);     // [4096][1024] X hi (reused as Y hi)
    ushort* Xl   = (ushort*)(ws + 58720256);     // [4096][1024] X lo (reused as Y lo)
    ushort* Wih  = (ushort*)(ws + 67108864);     // [3072][1024] hi
    ushort* Wil  = (ushort*)(ws + 73400320);
    ushort* Woh  = (ushort*)(ws + 79691776);     // [1024][1024] hi
    ushort* Wol  = (ushort*)(ws + 81788928);
    ushort* Yh = Xh;   // X dead after QKV projection
    ushort* Yl = Xl;

    // 0) split fp32 -> bf16 hi/lo
    split_f32_kernel<<<4096, 256, 0, stream>>>((const float4*)x,
        (ushort4*)Xh, (ushort4*)Xl, 1048576);
    split_f32_kernel<<<3072, 256, 0, stream>>>((const float4*)w_in,
        (ushort4*)Wih, (ushort4*)Wil, 786432);
    split_f32_kernel<<<1024, 256, 0, stream>>>((const float4*)w_out,
        (ushort4*)Woh, (ushort4*)Wol, 262144);

    // 1) QKV projection -> pre-split bf16 Q,K (Q scaled 1/8) + transposed V
    gemm_qkv<<<dim3(E3 / 128, 4096 / 128), 256, 0, stream>>>(
        Xh, Xl, Wih, Wil, b_in, qkvh, qkvl, Vth, Vtl);

    // 2) MFMA flash attention (double-buffered) -> Y (split bf16)
    attn_mfma<<<dim3(S_LEN / 64, 2 * NH), 256, 0, stream>>>(
        qkvh, qkvl, Vth, Vtl, mask, Yh, Yl);

    // 3) out projection: out = Y @ W_out^T + b_out (fp32 out)
    gemm_split_bf16<<<dim3(EMB / 128, 4096 / 128), 256, 0, stream>>>(
        Yh, Yl, Woh, Wol, b_out, out, 4096, EMB, EMB);
}